// Round 13
// baseline (143.783 us; speedup 1.0000x reference)
//
#include <hip/hip_runtime.h>
#include <math.h>

#define BB 64
#define SS 512
#define DD 256
#define HH 4
#define SCALE 0.0625f  // 1/sqrt(256)

__device__ inline float wave_red_sum(float v) {
#pragma unroll
    for (int off = 32; off > 0; off >>= 1) v += __shfl_xor(v, off, 64);
    return v;
}
__device__ inline float wave_red_max(float v) {
#pragma unroll
    for (int off = 32; off > 0; off >>= 1) v = fmaxf(v, __shfl_xor(v, off, 64));
    return v;
}

// K1: blocks (h, ds): q[h][:] (redundant x4), kb[h], kq[h][ds*64..+64)
__global__ __launch_bounds__(256) void setup_kernel(const float* __restrict__ seeds,
                                                    const float* __restrict__ Wq,
                                                    const float* __restrict__ bq,
                                                    const float* __restrict__ Wk,
                                                    const float* __restrict__ bk,
                                                    float* __restrict__ kqf,
                                                    float* __restrict__ kbg) {
    int blk = blockIdx.x, tid = threadIdx.x, w = tid >> 6, lane = tid & 63;
    int h = blk >> 2, ds = blk & 3;
    __shared__ float ql[DD];
    __shared__ float red[4][64];
    __shared__ float rb[4];
    float qv = bq[h * DD + tid];
#pragma unroll 8
    for (int d = 0; d < DD; ++d)
        qv = fmaf(seeds[d], Wq[(size_t)d * (HH * DD) + h * DD + tid], qv);
    ql[tid] = qv;
    float t1 = wave_red_sum(bk[h * DD + tid] * qv);
    if (lane == 0) rb[w] = t1;
    __syncthreads();
    if (tid == 0) kbg[h] = rb[0] + rb[1] + rb[2] + rb[3];  // 4 blocks write same value: benign
    int dl = tid & 63, ec = tid >> 6;
    int d = ds * 64 + dl;
    const float4* wrow = reinterpret_cast<const float4*>(Wk + (size_t)d * (HH * DD) + h * DD + ec * 64);
    const float4* qq4 = reinterpret_cast<const float4*>(&ql[ec * 64]);
    float acc = 0.f;
#pragma unroll
    for (int e4 = 0; e4 < 16; ++e4) {
        float4 wv = wrow[e4], qq = qq4[e4];
        acc += wv.x * qq.x + wv.y * qq.y + wv.z * qq.z + wv.w * qq.w;
    }
    red[ec][dl] = acc;
    __syncthreads();
    if (tid < 64) kqf[h * DD + ds * 64 + tid] = red[0][tid] + red[1][tid] + red[2][tid] + red[3][tid];
}

// K2: flash. block = (b, st) of 64 rows. x tile in LDS as XOR-swizzled float4.
__global__ __launch_bounds__(256) void flash_kernel(const float* __restrict__ x,
                                                    const int* __restrict__ mask,
                                                    const float* __restrict__ kqf,
                                                    const float* __restrict__ kbg,
                                                    float* __restrict__ xp,
                                                    float* __restrict__ mt,
                                                    float* __restrict__ lt) {
    int blk = blockIdx.x, tid = threadIdx.x, w = tid >> 6, lane = tid & 63;
    int b = blk >> 3, st = blk & 7;
    __shared__ __align__(16) float4 xt4[64][64];    // 64 KB
    __shared__ __align__(16) float part[4][2][64];  // aliased as sc[256] after softmax
    float* sc = &part[0][0][0];

    const float4* xg = reinterpret_cast<const float4*>(x + ((size_t)b * SS + st * 64) * DD);
#pragma unroll
    for (int c = 0; c < 16; ++c) {
        int f = c * 256 + tid;
        int row = f >> 6, ch = f & 63;
        xt4[row][ch ^ (row & 7)] = xg[f];
    }
    __syncthreads();

    {
        int s = lane;
        int hp = w >> 1, kk = w & 1;
        int off = __builtin_amdgcn_readfirstlane(hp * 2 * DD + kk * 128);
        const float4* kA4 = reinterpret_cast<const float4*>(kqf + off);
        const float4* kB4 = reinterpret_cast<const float4*>(kqf + off + DD);
        int sx = s & 7;
        float a0 = 0.f, a1 = 0.f;
#pragma unroll
        for (int k4 = 0; k4 < 32; ++k4) {
            float4 xv = xt4[s][(kk * 32 + k4) ^ sx];
            float4 av = kA4[k4], bv = kB4[k4];
            a0 += xv.x * av.x + xv.y * av.y + xv.z * av.z + xv.w * av.w;
            a1 += xv.x * bv.x + xv.y * bv.y + xv.z * bv.z + xv.w * bv.w;
        }
        part[w][0][s] = a0;
        part[w][1][s] = a1;
    }
    __syncthreads();

    {
        int s = lane, h = w;
        float v = part[2 * (h >> 1)][h & 1][s] + part[2 * (h >> 1) + 1][h & 1][s];
        float score = (v + kbg[h]) * SCALE + (1.f - (float)mask[b * SS + st * 64 + s]) * -1e9f;
        float m = wave_red_max(score);
        float p = __expf(score - m);
        float l = wave_red_sum(p);
        __syncthreads();
        sc[h * 64 + s] = p;
        if (lane == 0) {
            mt[blk * 4 + h] = m;
            lt[blk * 4 + h] = l;
        }
    }
    __syncthreads();

    {
        float o0 = 0.f, o1 = 0.f, o2 = 0.f, o3 = 0.f;
        int ch = tid >> 2, sub = tid & 3;
#pragma unroll 4
        for (int sb = 0; sb < 16; ++sb) {
            float4 p0 = *reinterpret_cast<const float4*>(&sc[0 * 64 + 4 * sb]);
            float4 p1 = *reinterpret_cast<const float4*>(&sc[1 * 64 + 4 * sb]);
            float4 p2 = *reinterpret_cast<const float4*>(&sc[2 * 64 + 4 * sb]);
            float4 p3 = *reinterpret_cast<const float4*>(&sc[3 * 64 + 4 * sb]);
#pragma unroll
            for (int j = 0; j < 4; ++j) {
                int row = 4 * sb + j;
                float xv = reinterpret_cast<const float*>(&xt4[row][ch ^ (row & 7)])[sub];
                float pj0 = (j == 0) ? p0.x : (j == 1) ? p0.y : (j == 2) ? p0.z : p0.w;
                float pj1 = (j == 0) ? p1.x : (j == 1) ? p1.y : (j == 2) ? p1.z : p1.w;
                float pj2 = (j == 0) ? p2.x : (j == 1) ? p2.y : (j == 2) ? p2.z : p2.w;
                float pj3 = (j == 0) ? p3.x : (j == 1) ? p3.y : (j == 2) ? p3.z : p3.w;
                o0 = fmaf(pj0, xv, o0);
                o1 = fmaf(pj1, xv, o1);
                o2 = fmaf(pj2, xv, o2);
                o3 = fmaf(pj3, xv, o3);
            }
        }
        float* xpo = xp + (size_t)blk * 4 * DD;
        xpo[0 * DD + tid] = o0;
        xpo[1 * DD + tid] = o1;
        xpo[2 * DD + tid] = o2;
        xpo[3 * DD + tid] = o3;
    }
}

// K3 (merged ovwo+ln): block b, 1024 threads = (h, e).
// combine tiles -> xl[h][e]; ol = bv + xl*Wv; pl = ol*Wo; LN over sum_h pl + bo + seeds.
__global__ __launch_bounds__(1024) void ovwo_ln_kernel(const float* __restrict__ xp,
                                                       const float* __restrict__ mt,
                                                       const float* __restrict__ lt,
                                                       const float* __restrict__ Wv,
                                                       const float* __restrict__ bv,
                                                       const float* __restrict__ Wo,
                                                       const float* __restrict__ bo,
                                                       const float* __restrict__ seeds,
                                                       const float* __restrict__ gamma,
                                                       const float* __restrict__ beta,
                                                       float* __restrict__ out) {
    int b = blockIdx.x, tid = threadIdx.x;
    int h = tid >> 8, e = tid & 255;
    int w = tid >> 6, lane = tid & 63;
    __shared__ float xl[HH][DD];
    __shared__ float ol[HH][DD];
    __shared__ float pl[HH][DD];
    __shared__ float r1[4], r2[4];

    // combine tiles (mt/lt wave-uniform -> scalar loads)
    float M = -3.0e38f;
#pragma unroll
    for (int t = 0; t < 8; ++t) M = fmaxf(M, mt[(b * 8 + t) * 4 + h]);
    float L = 0.f;
    float co[8];
#pragma unroll
    for (int t = 0; t < 8; ++t) {
        co[t] = __expf(mt[(b * 8 + t) * 4 + h] - M);
        L += lt[(b * 8 + t) * 4 + h] * co[t];
    }
    float invL = 1.0f / L;
    float xb = 0.f;
#pragma unroll
    for (int t = 0; t < 8; ++t) xb += co[t] * xp[((size_t)(b * 8 + t) * 4 + h) * DD + e];
    xl[h][e] = xb * invL;
    __syncthreads();

    // Wv GEMV: ol[h][e] = bv[h,e] + sum_d xl[h][d] * Wv[d,h,e]  (xl broadcast, Wv coalesced)
    float acc = bv[h * DD + e];
    const float* wv = Wv + h * DD + e;
#pragma unroll 8
    for (int d = 0; d < DD; ++d) acc = fmaf(xl[h][d], wv[(size_t)d * (HH * DD)], acc);
    ol[h][e] = acc;
    __syncthreads();

    // Wo GEMV: pl[h][d] = sum_e ol[h][e] * Wo[h,e,d]   (thread reuses e as d)
    float a2 = 0.f;
    const float* wo = Wo + (size_t)(h * DD) * DD + e;
#pragma unroll 8
    for (int ee = 0; ee < DD; ++ee) a2 = fmaf(ol[h][ee], wo[(size_t)ee * DD], a2);
    pl[h][e] = a2;
    __syncthreads();

    // LayerNorm on threads 0..255 (waves 0..3); all threads hit the barriers
    float accn = 0.f, dv = 0.f;
    if (tid < DD) {
        accn = bo[tid] + seeds[tid] + pl[0][tid] + pl[1][tid] + pl[2][tid] + pl[3][tid];
        float t1 = wave_red_sum(accn);
        if (lane == 0) r1[w] = t1;
    }
    __syncthreads();
    float mu = (r1[0] + r1[1] + r1[2] + r1[3]) * (1.0f / DD);
    if (tid < DD) {
        dv = accn - mu;
        float t2 = wave_red_sum(dv * dv);
        if (lane == 0) r2[w] = t2;
    }
    __syncthreads();
    if (tid < DD) {
        float var = (r2[0] + r2[1] + r2[2] + r2[3]) * (1.0f / DD);
        out[(size_t)b * DD + tid] = dv * rsqrtf(var + 1e-6f) * gamma[tid] + beta[tid];
    }
}

extern "C" void kernel_launch(void* const* d_in, const int* in_sizes, int n_in,
                              void* d_out, int out_size, void* d_ws, size_t ws_size,
                              hipStream_t stream) {
    const float* x = (const float*)d_in[0];
    const int* mask = (const int*)d_in[1];
    const float* seeds = (const float*)d_in[2];
    const float* Wq = (const float*)d_in[3];
    const float* bq = (const float*)d_in[4];
    const float* Wk = (const float*)d_in[5];
    const float* bk = (const float*)d_in[6];
    const float* Wv = (const float*)d_in[7];
    const float* bv = (const float*)d_in[8];
    const float* Wo = (const float*)d_in[9];
    const float* bo = (const float*)d_in[10];
    const float* gamma = (const float*)d_in[11];
    const float* beta = (const float*)d_in[12];
    float* out = (float*)d_out;

    float* ws = (float*)d_ws;
    float* kqf = ws;              // 1024
    float* kbg = ws + 1024;       // 4 (+12 pad)
    float* mt  = ws + 1040;       // 512*4 = 2048
    float* lt  = ws + 3088;       // 512*4 = 2048
    float* xp  = ws + 5136;       // 512*4*256 = 524288

    setup_kernel<<<16, 256, 0, stream>>>(seeds, Wq, bq, Wk, bk, kqf, kbg);
    flash_kernel<<<BB * 8, 256, 0, stream>>>(x, mask, kqf, kbg, xp, mt, lt);
    ovwo_ln_kernel<<<BB, 1024, 0, stream>>>(xp, mt, lt, Wv, bv, Wo, bo, seeds, gamma, beta, out);
}